// Round 4
// baseline (452.880 us; speedup 1.0000x reference)
//
#include <hip/hip_runtime.h>
#include <math.h>

typedef __bf16 bf16x8 __attribute__((ext_vector_type(8)));
typedef __bf16 bf16x4 __attribute__((ext_vector_type(4)));
typedef float  f32x4  __attribute__((ext_vector_type(4)));
typedef short  s16x4  __attribute__((ext_vector_type(4)));

// Problem constants
constexpr int B_  = 128;
constexpr int M_  = 512;
constexpr int L_  = 1024;
constexpr int H_  = 64;
constexpr int KL_ = 1536;

// Tiling: 64 q-rows x 64 k-cols per tile; 4 waves = 2 row-halves (a) x 2 col-halves (c)
constexpr int BM  = 64;
constexpr int KT  = 64;
constexpr int NT  = 17;              // 17*64 = 1088 covers the 1024-band + 64-row skew

// LDS layout — exactly 40960 B -> 4 blocks/CU at 160 KiB (single-phase: grid = 4/CU)
constexpr int OFF_VT   = 0;          // vt[64][64] bf16, single-buffered, XOR-swizzled (8192 B)
constexpr int OFF_PPOS = 8192;       // ppos[64][256] bf16, XOR-swizzled (32768 B)
constexpr int SMEM_BYTES = 40960;
// epilogue overlays (after final barrier):
constexpr int OFF_OBUF = 0;          // [128][36] f32 partial O (18432 B)
constexpr int OFF_LSUM = 18432;      // [128] f32 row sums
constexpr int OBS = 36;

// PE pre-pack table: [ch(16)][nt(2)][c(2)] blocks of [lane(64)][frag f(2)][j(8)] bf16
constexpr size_t PET_BYTES = 16 * 2 * 2 * 64 * 16 * sizeof(__bf16);  // 131072

#define MFMA32(A, B, C) __builtin_amdgcn_mfma_f32_16x16x32_bf16((A), (B), (C), 0, 0, 0)

static __device__ __forceinline__ f32x4 mfma_pv(bf16x4 a, bf16x4 b, f32x4 c) {
  return __builtin_amdgcn_mfma_f32_16x16x16bf16_1k(
      __builtin_bit_cast(s16x4, a), __builtin_bit_cast(s16x4, b), c, 0, 0, 0);
}

// exp((s+pe)/8) = exp2((s+pe) * 0.125*log2(e))
constexpr float EXP2_SCALE = 0.18033688011112042f;

// XOR swizzles (16-byte granule = 8 bf16): both buffers have row stride === 0 mod 32 banks,
// so spread banks by XORing bits[5:3] of the bf16 column with (row&7). All b64 accesses
// use 4-aligned column bases -> the xor keeps them 4-aligned inside one granule.
static __device__ __forceinline__ int vt_idx(int hrow, int kv) {
  return hrow * 64 + (kv ^ ((hrow & 7) << 3));
}
static __device__ __forceinline__ int pp_idx(int row, int col) {  // col in [0,256)
  return row * 256 + (col ^ ((row & 7) << 3));
}

// ---- init kernel: pack PE (1 x 64 x 1024 f32) into lane-fragment-ordered bf16 table ----
__global__ void pe_pack(const float* __restrict__ PE, __bf16* __restrict__ PET) {
  const int gid = blockIdx.x * 256 + threadIdx.x;   // 65536 = one bf16 each
  const int j   = gid & 7;
  const int f   = (gid >> 3) & 1;
  const int ln  = (gid >> 4) & 63;
  const int blk = gid >> 10;                        // = ch*4 + nt*2 + c
  const int c   = blk & 1;
  const int nt  = (blk >> 1) & 1;
  const int ch  = blk >> 2;
  const int nid = ln & 15, qid = ln >> 4;
  const int h = 8 * qid + j + 32 * f;
  const int l = 64 * ch + 32 * c + 16 * nt + nid;
  PET[gid] = (__bf16)PE[h * L_ + l];
}

template <bool USE_PET>
__global__ __launch_bounds__(256, 4)
void seqattn_v8(const float* __restrict__ Q, const float* __restrict__ K,
                const float* __restrict__ V, const float* __restrict__ PE,
                const __bf16* __restrict__ PET, float* __restrict__ O) {
  __shared__ alignas(16) char smem[SMEM_BYTES];
  __bf16* vtb  = (__bf16*)(smem + OFF_VT);
  __bf16* ppos = (__bf16*)(smem + OFF_PPOS);

  const int tid  = threadIdx.x;
  const int w    = tid >> 6;
  const int lane = tid & 63;
  const int nid  = lane & 15;
  const int qid  = lane >> 4;
  const int a    = w >> 1;            // q-rows 32a..32a+31
  const int c    = w & 1;            // tile cols 32c..32c+31
  const int b    = blockIdx.x;
  const int m0   = blockIdx.y * BM;

  // ---- Q fragments (MFMA *B* operand after the operand swap) ----
  bf16x8 aq[2][2];
  #pragma unroll
  for (int it = 0; it < 2; ++it) {
    const float* qg = &Q[((size_t)b * M_ + m0 + 32 * a + 16 * it + nid) * H_];
    #pragma unroll
    for (int j = 0; j < 8; ++j) {
      aq[it][0][j] = (__bf16)qg[8 * qid + j];
      aq[it][1][j] = (__bf16)qg[32 + 8 * qid + j];
    }
  }

  f32x4 o[2][4];
  float lpart[2] = {0.f, 0.f};
  #pragma unroll
  for (int it = 0; it < 2; ++it)
    #pragma unroll
    for (int ht = 0; ht < 4; ++ht) o[it][ht] = (f32x4){0.f, 0.f, 0.f, 0.f};

  const int vj = (tid & 15) * 4, vh = (tid >> 4) * 4; // V staging: 4x4 reg transpose

  // fallback PE gather base (USE_PET=false only)
  const float* peg = &PE[(size_t)(8 * qid) * L_ + 32 * c + nid];

  // ---------------- prologue ----------------
  // K tile 0 A-frags straight from global
  bf16x8 ak[2][2];
  #pragma unroll
  for (int nt = 0; nt < 2; ++nt) {
    const float* kg = &K[((size_t)b * KL_ + m0 + 32 * c + 16 * nt + nid) * H_ + 8 * qid];
    const f32x4 k0 = *(const f32x4*)kg;
    const f32x4 k1 = *(const f32x4*)(kg + 4);
    const f32x4 k2 = *(const f32x4*)(kg + 32);
    const f32x4 k3 = *(const f32x4*)(kg + 36);
    #pragma unroll
    for (int j = 0; j < 4; ++j) {
      ak[nt][0][j] = (__bf16)k0[j]; ak[nt][0][4 + j] = (__bf16)k1[j];
      ak[nt][1][j] = (__bf16)k2[j]; ak[nt][1][4 + j] = (__bf16)k3[j];
    }
  }
  // V tile 0
  f32x4 vr[4];
  {
    const float* vg = &V[((size_t)b * KL_ + m0 + vj) * H_ + vh];
    #pragma unroll
    for (int e = 0; e < 4; ++e) vr[e] = *(const f32x4*)(vg + e * H_);
  }
  // QPE chunk 0 -> ppos (skewed: col = (l+row)&255)
  {
    const f32x4 z = {0.f, 0.f, 0.f, 0.f};
    bf16x8 pf0[2], pf1[2];
    if constexpr (USE_PET) {
      const __bf16* pb = PET + (size_t)c * 1024 + (size_t)lane * 16;  // ch=0, nt=0
      pf0[0] = *(const bf16x8*)pb;          pf1[0] = *(const bf16x8*)(pb + 8);
      pf0[1] = *(const bf16x8*)(pb + 2048); pf1[1] = *(const bf16x8*)(pb + 2048 + 8);
    } else {
      #pragma unroll
      for (int nt = 0; nt < 2; ++nt)
        #pragma unroll
        for (int j = 0; j < 8; ++j) {
          pf0[nt][j] = (__bf16)peg[(size_t)j * L_ + 16 * nt];
          pf1[nt][j] = (__bf16)peg[(size_t)(32 + j) * L_ + 16 * nt];
        }
    }
    #pragma unroll
    for (int nt = 0; nt < 2; ++nt) {
      #pragma unroll
      for (int it = 0; it < 2; ++it) {
        f32x4 pp = MFMA32(pf0[nt], aq[it][0], z);
        pp = MFMA32(pf1[nt], aq[it][1], pp);
        const int row = 32 * a + 16 * it + nid;
        const int cb  = 32 * c + 16 * nt + 4 * qid + row;   // ch=0: l + row
        #pragma unroll
        for (int r = 0; r < 4; ++r)
          ppos[pp_idx(row, (cb + r) & 255)] = (__bf16)pp[r];
      }
    }
  }
  // stage V tile 0
  #pragma unroll
  for (int e = 0; e < 4; ++e) {
    bf16x4 y = {(__bf16)vr[0][e], (__bf16)vr[1][e], (__bf16)vr[2][e], (__bf16)vr[3][e]};
    *(bf16x4*)&vtb[vt_idx(vh + e, vj)] = y;
  }
  __syncthreads();

  // ---------------- main loop: 2 barriers per tile (single-buffered vt) ----------------
  for (int t = 0; t < NT; ++t) {
    // A: ppos reads for this tile (slot t&3; aligned b64; swizzled)
    bf16x4 pe4[2][2];
    #pragma unroll
    for (int it = 0; it < 2; ++it) {
      const int row = 32 * a + 16 * it + nid;
      #pragma unroll
      for (int nt = 0; nt < 2; ++nt)
        pe4[it][nt] = *(const bf16x4*)
            &ppos[pp_idx(row, 64 * (t & 3) + 32 * c + 16 * nt + 4 * qid)];
    }

    // A2: PET loads for chunk t+1 (2x16B coalesced, L2-resident)
    bf16x8 pf0[2], pf1[2];
    if (t < 15) {
      if constexpr (USE_PET) {
        const __bf16* pb = PET + ((size_t)(t + 1) * 4 + c) * 1024 + (size_t)lane * 16;
        pf0[0] = *(const bf16x8*)pb;          pf1[0] = *(const bf16x8*)(pb + 8);
        pf0[1] = *(const bf16x8*)(pb + 2048); pf1[1] = *(const bf16x8*)(pb + 2048 + 8);
      } else {
        const float* pc = peg + (t + 1) * 64;
        #pragma unroll
        for (int nt = 0; nt < 2; ++nt)
          #pragma unroll
          for (int j = 0; j < 8; ++j) {
            pf0[nt][j] = (__bf16)pc[(size_t)j * L_ + 16 * nt];
            pf1[nt][j] = (__bf16)pc[(size_t)(32 + j) * L_ + 16 * nt];
          }
      }
    }

    // B: prefetch K/V tile t+1 into registers
    bf16x8 akn[2][2];
    if (t < 16) {
      const int j1 = m0 + KT * (t + 1);
      #pragma unroll
      for (int nt = 0; nt < 2; ++nt) {
        const float* kg = &K[((size_t)b * KL_ + j1 + 32 * c + 16 * nt + nid) * H_ + 8 * qid];
        const f32x4 k0 = *(const f32x4*)kg;
        const f32x4 k1 = *(const f32x4*)(kg + 4);
        const f32x4 k2 = *(const f32x4*)(kg + 32);
        const f32x4 k3 = *(const f32x4*)(kg + 36);
        #pragma unroll
        for (int j = 0; j < 4; ++j) {
          akn[nt][0][j] = (__bf16)k0[j]; akn[nt][0][4 + j] = (__bf16)k1[j];
          akn[nt][1][j] = (__bf16)k2[j]; akn[nt][1][4 + j] = (__bf16)k3[j];
        }
      }
      const float* vg = &V[((size_t)b * KL_ + j1 + vj) * H_ + vh];
      #pragma unroll
      for (int e = 0; e < 4; ++e) vr[e] = *(const f32x4*)(vg + e * H_);
    }

    const f32x4 z = {0.f, 0.f, 0.f, 0.f};

    // C: QK^T swapped: S^T = mfma(A=K, B=Q); lane(nid,qid) reg r ->
    //    S[qrow=32a+16it+nid][kcol=64t+32c+16nt+4qid+r]
    f32x4 s[2][2];
    #pragma unroll
    for (int nt = 0; nt < 2; ++nt)
      #pragma unroll
      for (int it = 0; it < 2; ++it) {
        s[it][nt] = MFMA32(ak[nt][0], aq[it][0], z);
        s[it][nt] = MFMA32(ak[nt][1], aq[it][1], s[it][nt]);
      }

    // D: QPE chunk t+1 -> skewed stores (slots (t+1..t+3)&3; never slot t&3)
    if (t < 15) {
      const int chb = 64 * (t + 1);
      #pragma unroll
      for (int nt = 0; nt < 2; ++nt) {
        #pragma unroll
        for (int it = 0; it < 2; ++it) {
          f32x4 pp = MFMA32(pf0[nt], aq[it][0], z);
          pp = MFMA32(pf1[nt], aq[it][1], pp);
          const int row = 32 * a + 16 * it + nid;
          const int cb  = chb + 32 * c + 16 * nt + 4 * qid + row;
          #pragma unroll
          for (int r = 0; r < 4; ++r)
            ppos[pp_idx(row, (cb + r) & 255)] = (__bf16)pp[r];
        }
      }
    }

    // E: softmax: exp in-register, build PV A-frags
    const bool edge = (t == 0) || (t == 16);
    bf16x4 pa[2][2];
    #pragma unroll
    for (int it = 0; it < 2; ++it) {
      const int row = 32 * a + 16 * it + nid;
      #pragma unroll
      for (int nt = 0; nt < 2; ++nt) {
        const int lb = KT * t + 32 * c + 16 * nt + 4 * qid - row;
        #pragma unroll
        for (int r = 0; r < 4; ++r) {
          const int l = lb + r;
          float p;
          if (!edge || (unsigned)l < 1024u)
            p = exp2f((s[it][nt][r] + (float)pe4[it][nt][r]) * EXP2_SCALE);
          else
            p = 0.f;
          lpart[it] += p;
          pa[it][nt][r] = (__bf16)p;
        }
      }
    }

    // F: PV: 16x16x16, A = pa (regs), B = V^T from LDS (swizzled)
    #pragma unroll
    for (int nt = 0; nt < 2; ++nt) {
      bf16x4 vb[4];
      #pragma unroll
      for (int ht = 0; ht < 4; ++ht)
        vb[ht] = *(const bf16x4*)&vtb[vt_idx(16 * ht + nid, 32 * c + 16 * nt + 4 * qid)];
      #pragma unroll
      for (int it = 0; it < 2; ++it)
        #pragma unroll
        for (int ht = 0; ht < 4; ++ht)
          o[it][ht] = mfma_pv(pa[it][nt], vb[ht], o[it][ht]);
    }

    __syncthreads();   // B1: all vt reads + slot-t ppos reads done

    // H: write V tile t+1 into vt; rotate K frags
    if (t < 16) {
      #pragma unroll
      for (int e = 0; e < 4; ++e) {
        bf16x4 y = {(__bf16)vr[0][e], (__bf16)vr[1][e], (__bf16)vr[2][e], (__bf16)vr[3][e]};
        *(bf16x4*)&vtb[vt_idx(vh + e, vj)] = y;
      }
      #pragma unroll
      for (int nt = 0; nt < 2; ++nt) {
        ak[nt][0] = akn[nt][0];
        ak[nt][1] = akn[nt][1];
      }
    }
    __syncthreads();   // B2: vt tile t+1 + ppos chunk t+1 visible
  }

  // ---------------- epilogue: merge c-halves, normalize, store ----------------
  float* lsum = (float*)(smem + OFF_LSUM);
  float* obuf = (float*)(smem + OFF_OBUF);

  #pragma unroll
  for (int it = 0; it < 2; ++it) {
    float v = lpart[it];
    v += __shfl_xor(v, 16);
    v += __shfl_xor(v, 32);
    lpart[it] = v;
  }
  if (qid == 0) {
    #pragma unroll
    for (int it = 0; it < 2; ++it)
      lsum[c * 64 + 32 * a + 16 * it + nid] = lpart[it];
  }
  if (c == 1) {
    #pragma unroll
    for (int it = 0; it < 2; ++it)
      #pragma unroll
      for (int ht = 0; ht < 4; ++ht)
        *(f32x4*)&obuf[(a * 64 + 16 * ht + nid) * OBS + 16 * it + 4 * qid] = o[it][ht];
  }
  __syncthreads();
  if (c == 0) {
    float inv[2][4];
    #pragma unroll
    for (int it = 0; it < 2; ++it)
      #pragma unroll
      for (int r = 0; r < 4; ++r) {
        const int row = 32 * a + 16 * it + 4 * qid + r;
        inv[it][r] = 1.f / (lsum[row] + lsum[64 + row]);
      }
    #pragma unroll
    for (int it = 0; it < 2; ++it) {
      #pragma unroll
      for (int ht = 0; ht < 4; ++ht) {
        f32x4 oo = o[it][ht] +
                   *(const f32x4*)&obuf[(a * 64 + 16 * ht + nid) * OBS + 16 * it + 4 * qid];
        #pragma unroll
        for (int r = 0; r < 4; ++r) {
          const int row = 32 * a + 16 * it + 4 * qid + r;
          O[((size_t)b * M_ + m0 + row) * H_ + 16 * ht + nid] = oo[r] * inv[it][r];
        }
      }
    }
  }
}

extern "C" void kernel_launch(void* const* d_in, const int* in_sizes, int n_in,
                              void* d_out, int out_size, void* d_ws, size_t ws_size,
                              hipStream_t stream) {
  const float* Q  = (const float*)d_in[0];   // B x M x H
  const float* K  = (const float*)d_in[1];   // B x (M+L) x H
  const float* V  = (const float*)d_in[2];   // B x (M+L) x H
  const float* PE = (const float*)d_in[3];   // 1 x H x L
  float* O = (float*)d_out;                  // B x M x H

  dim3 grid(B_, M_ / BM);                    // 1024 blocks = exactly 4 per CU (single phase)
  if (d_ws != nullptr && ws_size >= PET_BYTES) {
    // init kernel runs in-graph on every launch -> robust to workspace re-poisoning
    __bf16* PET = (__bf16*)d_ws;
    hipLaunchKernelGGL(pe_pack, dim3(256), dim3(256), 0, stream, PE, PET);
    hipLaunchKernelGGL(seqattn_v8<true>, grid, dim3(256), 0, stream, Q, K, V, PE, PET, O);
  } else {
    hipLaunchKernelGGL(seqattn_v8<false>, grid, dim3(256), 0, stream, Q, K, V, PE,
                       (const __bf16*)nullptr, O);
  }
}

// Round 5
// 293.721 us; speedup vs baseline: 1.5419x; 1.5419x over previous
//
#include <hip/hip_runtime.h>
#include <math.h>

typedef __bf16 bf16x8 __attribute__((ext_vector_type(8)));
typedef __bf16 bf16x4 __attribute__((ext_vector_type(4)));
typedef float  f32x4  __attribute__((ext_vector_type(4)));
typedef short  s16x4  __attribute__((ext_vector_type(4)));

// Problem constants
constexpr int B_  = 128;
constexpr int M_  = 512;
constexpr int L_  = 1024;
constexpr int H_  = 64;
constexpr int KL_ = 1536;

// Tiling: 64 q-rows x 64 k-cols per tile; 4 waves = 2 row-halves (a) x 2 col-halves (c)
constexpr int BM  = 64;
constexpr int KT  = 64;
constexpr int NT  = 17;              // 17*64 = 1088 covers the 1024-band + 64-row skew

// LDS layout — 49152 B -> 3 blocks/CU at 160 KiB
constexpr int OFF_VT   = 0;          // vt[2][64][64] bf16, double-buffered, swizzled (16384 B)
constexpr int OFF_PPOS = 16384;      // ppos[64][256] bf16, swizzled (32768 B)
constexpr int SMEM_BYTES = 49152;
// epilogue overlays (after final barrier):
constexpr int OFF_OBUF = 0;          // [128][36] f32 partial O (18432 B)
constexpr int OFF_LSUM = 18432;      // [128] f32 row sums
constexpr int OBS = 36;

// PE pre-pack table: [ch(16)][nt(2)][c(2)] blocks of [lane(64)][frag f(2)][j(8)] bf16
constexpr size_t PET_BYTES = 16 * 2 * 2 * 64 * 16 * sizeof(__bf16);  // 131072

#define MFMA32(A, B, C) __builtin_amdgcn_mfma_f32_16x16x32_bf16((A), (B), (C), 0, 0, 0)

static __device__ __forceinline__ f32x4 mfma_pv(bf16x4 a, bf16x4 b, f32x4 c) {
  return __builtin_amdgcn_mfma_f32_16x16x16bf16_1k(
      __builtin_bit_cast(s16x4, a), __builtin_bit_cast(s16x4, b), c, 0, 0, 0);
}

// exp((s+pe)/8) = exp2((s+pe) * 0.125*log2(e))
constexpr float EXP2_SCALE = 0.18033688011112042f;

// 4-bit granule XOR swizzles. Both buffers have row stride === 0 mod 128B (bank wrap),
// so bank depends only on col; XOR the 8B-granule index (col bits 2..5) with (row&15).
// Every b64 access in the kernel uses a 4-aligned bf16 column base, so the xor keeps
// accesses granule-aligned, and each read/write pattern spreads to exactly 4 lanes per
// bank-pair (the wave64 b64 minimum -> no counted conflicts).
static __device__ __forceinline__ int vt_idx(int hrow, int kv) {   // kv in [0,64)
  return hrow * 64 + (kv ^ ((hrow & 15) << 2));
}
static __device__ __forceinline__ int pp_idx(int row, int col) {   // col in [0,256)
  return row * 256 + (col ^ ((row & 15) << 2));
}

// ---- init kernel: pack PE (1 x 64 x 1024 f32) into lane-fragment-ordered bf16 table ----
__global__ void pe_pack(const float* __restrict__ PE, __bf16* __restrict__ PET) {
  const int gid = blockIdx.x * 256 + threadIdx.x;   // 65536 = one bf16 each
  const int j   = gid & 7;
  const int f   = (gid >> 3) & 1;
  const int ln  = (gid >> 4) & 63;
  const int blk = gid >> 10;                        // = ch*4 + nt*2 + c
  const int c   = blk & 1;
  const int nt  = (blk >> 1) & 1;
  const int ch  = blk >> 2;
  const int nid = ln & 15, qid = ln >> 4;
  const int h = 8 * qid + j + 32 * f;
  const int l = 64 * ch + 32 * c + 16 * nt + nid;
  PET[gid] = (__bf16)PE[h * L_ + l];
}

template <bool USE_PET>
__global__ __launch_bounds__(256) __attribute__((amdgpu_waves_per_eu(3, 3)))
void seqattn_v9(const float* __restrict__ Q, const float* __restrict__ K,
                const float* __restrict__ V, const float* __restrict__ PE,
                const __bf16* __restrict__ PET, float* __restrict__ O) {
  __shared__ alignas(16) char smem[SMEM_BYTES];
  __bf16* vtb  = (__bf16*)(smem + OFF_VT);
  __bf16* ppos = (__bf16*)(smem + OFF_PPOS);

  const int tid  = threadIdx.x;
  const int w    = tid >> 6;
  const int lane = tid & 63;
  const int nid  = lane & 15;
  const int qid  = lane >> 4;
  const int a    = w >> 1;            // q-rows 32a..32a+31
  const int c    = w & 1;             // tile cols 32c..32c+31
  const int b    = blockIdx.x;        // batch on x -> same-batch blocks share an XCD
  const int m0   = blockIdx.y * BM;

  // ---- Q fragments (MFMA *B* operand after the operand swap) ----
  bf16x8 aq[2][2];
  #pragma unroll
  for (int it = 0; it < 2; ++it) {
    const float* qg = &Q[((size_t)b * M_ + m0 + 32 * a + 16 * it + nid) * H_];
    #pragma unroll
    for (int j = 0; j < 8; ++j) {
      aq[it][0][j] = (__bf16)qg[8 * qid + j];
      aq[it][1][j] = (__bf16)qg[32 + 8 * qid + j];
    }
  }

  f32x4 o[2][4];
  float lpart[2] = {0.f, 0.f};
  #pragma unroll
  for (int it = 0; it < 2; ++it)
    #pragma unroll
    for (int ht = 0; ht < 4; ++ht) o[it][ht] = (f32x4){0.f, 0.f, 0.f, 0.f};

  const int vj = (tid & 15) * 4, vh = (tid >> 4) * 4; // V staging: 4x4 reg transpose

  // fallback PE gather base (USE_PET=false only)
  const float* peg = &PE[(size_t)(8 * qid) * L_ + 32 * c + nid];

  // ---------------- prologue ----------------
  // K tile 0 A-frags straight from global
  bf16x8 ak[2][2];
  #pragma unroll
  for (int nt = 0; nt < 2; ++nt) {
    const float* kg = &K[((size_t)b * KL_ + m0 + 32 * c + 16 * nt + nid) * H_ + 8 * qid];
    const f32x4 k0 = *(const f32x4*)kg;
    const f32x4 k1 = *(const f32x4*)(kg + 4);
    const f32x4 k2 = *(const f32x4*)(kg + 32);
    const f32x4 k3 = *(const f32x4*)(kg + 36);
    #pragma unroll
    for (int j = 0; j < 4; ++j) {
      ak[nt][0][j] = (__bf16)k0[j]; ak[nt][0][4 + j] = (__bf16)k1[j];
      ak[nt][1][j] = (__bf16)k2[j]; ak[nt][1][4 + j] = (__bf16)k3[j];
    }
  }
  // V tile 0
  f32x4 vr[4];
  {
    const float* vg = &V[((size_t)b * KL_ + m0 + vj) * H_ + vh];
    #pragma unroll
    for (int e = 0; e < 4; ++e) vr[e] = *(const f32x4*)(vg + e * H_);
  }
  // QPE chunk 0 -> ppos (skewed: col = (l+row)&255)
  {
    const f32x4 z = {0.f, 0.f, 0.f, 0.f};
    bf16x8 pf0[2], pf1[2];
    if constexpr (USE_PET) {
      const __bf16* pb = PET + (size_t)c * 1024 + (size_t)lane * 16;  // ch=0, nt=0
      pf0[0] = *(const bf16x8*)pb;          pf1[0] = *(const bf16x8*)(pb + 8);
      pf0[1] = *(const bf16x8*)(pb + 2048); pf1[1] = *(const bf16x8*)(pb + 2048 + 8);
    } else {
      #pragma unroll
      for (int nt = 0; nt < 2; ++nt)
        #pragma unroll
        for (int j = 0; j < 8; ++j) {
          pf0[nt][j] = (__bf16)peg[(size_t)j * L_ + 16 * nt];
          pf1[nt][j] = (__bf16)peg[(size_t)(32 + j) * L_ + 16 * nt];
        }
    }
    #pragma unroll
    for (int nt = 0; nt < 2; ++nt) {
      #pragma unroll
      for (int it = 0; it < 2; ++it) {
        f32x4 pp = MFMA32(pf0[nt], aq[it][0], z);
        pp = MFMA32(pf1[nt], aq[it][1], pp);
        const int row = 32 * a + 16 * it + nid;
        const int cb  = 32 * c + 16 * nt + 4 * qid + row;   // ch=0: l + row
        #pragma unroll
        for (int r = 0; r < 4; ++r)
          ppos[pp_idx(row, (cb + r) & 255)] = (__bf16)pp[r];
      }
    }
  }
  // stage V tile 0 -> buf 0
  #pragma unroll
  for (int e = 0; e < 4; ++e) {
    bf16x4 y = {(__bf16)vr[0][e], (__bf16)vr[1][e], (__bf16)vr[2][e], (__bf16)vr[3][e]};
    *(bf16x4*)&vtb[vt_idx(vh + e, vj)] = y;
  }
  __syncthreads();

  // ---------------- main loop: ONE barrier per tile (double-buffered vt) ----------------
  for (int t = 0; t < NT; ++t) {
    // A: ppos reads for this tile (slot t&3; aligned b64; swizzled)
    bf16x4 pe4[2][2];
    #pragma unroll
    for (int it = 0; it < 2; ++it) {
      const int row = 32 * a + 16 * it + nid;
      #pragma unroll
      for (int nt = 0; nt < 2; ++nt)
        pe4[it][nt] = *(const bf16x4*)
            &ppos[pp_idx(row, 64 * (t & 3) + 32 * c + 16 * nt + 4 * qid)];
    }

    // A2: PET loads for chunk t+1 (2x16B coalesced, L2-resident)
    bf16x8 pf0[2], pf1[2];
    if (t < 15) {
      if constexpr (USE_PET) {
        const __bf16* pb = PET + ((size_t)(t + 1) * 4 + c) * 1024 + (size_t)lane * 16;
        pf0[0] = *(const bf16x8*)pb;          pf1[0] = *(const bf16x8*)(pb + 8);
        pf0[1] = *(const bf16x8*)(pb + 2048); pf1[1] = *(const bf16x8*)(pb + 2048 + 8);
      } else {
        const float* pc = peg + (t + 1) * 64;
        #pragma unroll
        for (int nt = 0; nt < 2; ++nt)
          #pragma unroll
          for (int j = 0; j < 8; ++j) {
            pf0[nt][j] = (__bf16)pc[(size_t)j * L_ + 16 * nt];
            pf1[nt][j] = (__bf16)pc[(size_t)(32 + j) * L_ + 16 * nt];
          }
      }
    }

    // B: prefetch K/V tile t+1 into registers
    bf16x8 akn[2][2];
    if (t < 16) {
      const int j1 = m0 + KT * (t + 1);
      #pragma unroll
      for (int nt = 0; nt < 2; ++nt) {
        const float* kg = &K[((size_t)b * KL_ + j1 + 32 * c + 16 * nt + nid) * H_ + 8 * qid];
        const f32x4 k0 = *(const f32x4*)kg;
        const f32x4 k1 = *(const f32x4*)(kg + 4);
        const f32x4 k2 = *(const f32x4*)(kg + 32);
        const f32x4 k3 = *(const f32x4*)(kg + 36);
        #pragma unroll
        for (int j = 0; j < 4; ++j) {
          akn[nt][0][j] = (__bf16)k0[j]; akn[nt][0][4 + j] = (__bf16)k1[j];
          akn[nt][1][j] = (__bf16)k2[j]; akn[nt][1][4 + j] = (__bf16)k3[j];
        }
      }
      const float* vg = &V[((size_t)b * KL_ + j1 + vj) * H_ + vh];
      #pragma unroll
      for (int e = 0; e < 4; ++e) vr[e] = *(const f32x4*)(vg + e * H_);
    }

    const __bf16* vtt = vtb + (t & 1) * 64 * 64;
    const f32x4 z = {0.f, 0.f, 0.f, 0.f};

    // C: QK^T swapped: S^T = mfma(A=K, B=Q); lane(nid,qid) reg r ->
    //    S[qrow=32a+16it+nid][kcol=64t+32c+16nt+4qid+r]
    f32x4 s[2][2];
    #pragma unroll
    for (int nt = 0; nt < 2; ++nt)
      #pragma unroll
      for (int it = 0; it < 2; ++it) {
        s[it][nt] = MFMA32(ak[nt][0], aq[it][0], z);
        s[it][nt] = MFMA32(ak[nt][1], aq[it][1], s[it][nt]);
      }

    // D: QPE chunk t+1 -> skewed stores (slots (t+1..t+3)&3; never slot t&3)
    if (t < 15) {
      const int chb = 64 * (t + 1);
      #pragma unroll
      for (int nt = 0; nt < 2; ++nt) {
        #pragma unroll
        for (int it = 0; it < 2; ++it) {
          f32x4 pp = MFMA32(pf0[nt], aq[it][0], z);
          pp = MFMA32(pf1[nt], aq[it][1], pp);
          const int row = 32 * a + 16 * it + nid;
          const int cb  = chb + 32 * c + 16 * nt + 4 * qid + row;
          #pragma unroll
          for (int r = 0; r < 4; ++r)
            ppos[pp_idx(row, (cb + r) & 255)] = (__bf16)pp[r];
        }
      }
    }

    // E: softmax: exp in-register, build PV A-frags
    const bool edge = (t == 0) || (t == 16);
    bf16x4 pa[2][2];
    #pragma unroll
    for (int it = 0; it < 2; ++it) {
      const int row = 32 * a + 16 * it + nid;
      #pragma unroll
      for (int nt = 0; nt < 2; ++nt) {
        const int lb = KT * t + 32 * c + 16 * nt + 4 * qid - row;
        #pragma unroll
        for (int r = 0; r < 4; ++r) {
          const int l = lb + r;
          float p;
          if (!edge || (unsigned)l < 1024u)
            p = exp2f((s[it][nt][r] + (float)pe4[it][nt][r]) * EXP2_SCALE);
          else
            p = 0.f;
          lpart[it] += p;
          pa[it][nt][r] = (__bf16)p;
        }
      }
    }

    // F: PV: 16x16x16, A = pa (regs), B = V^T from LDS (swizzled)
    #pragma unroll
    for (int nt = 0; nt < 2; ++nt) {
      bf16x4 vb[4];
      #pragma unroll
      for (int ht = 0; ht < 4; ++ht)
        vb[ht] = *(const bf16x4*)&vtt[vt_idx(16 * ht + nid, 32 * c + 16 * nt + 4 * qid)];
      #pragma unroll
      for (int it = 0; it < 2; ++it)
        #pragma unroll
        for (int ht = 0; ht < 4; ++ht)
          o[it][ht] = mfma_pv(pa[it][nt], vb[ht], o[it][ht]);
    }

    // G: stage prefetched V tile t+1 into the other buffer; rotate K frags
    if (t < 16) {
      __bf16* vtn = vtb + ((t + 1) & 1) * 64 * 64;
      #pragma unroll
      for (int e = 0; e < 4; ++e) {
        bf16x4 y = {(__bf16)vr[0][e], (__bf16)vr[1][e], (__bf16)vr[2][e], (__bf16)vr[3][e]};
        *(bf16x4*)&vtn[vt_idx(vh + e, vj)] = y;
      }
      #pragma unroll
      for (int nt = 0; nt < 2; ++nt) {
        ak[nt][0] = akn[nt][0];
        ak[nt][1] = akn[nt][1];
      }
    }
    __syncthreads();
  }

  // ---------------- epilogue: merge c-halves, normalize, store ----------------
  float* lsum = (float*)(smem + OFF_LSUM);
  float* obuf = (float*)(smem + OFF_OBUF);

  #pragma unroll
  for (int it = 0; it < 2; ++it) {
    float v = lpart[it];
    v += __shfl_xor(v, 16);
    v += __shfl_xor(v, 32);
    lpart[it] = v;
  }
  if (qid == 0) {
    #pragma unroll
    for (int it = 0; it < 2; ++it)
      lsum[c * 64 + 32 * a + 16 * it + nid] = lpart[it];
  }
  if (c == 1) {
    #pragma unroll
    for (int it = 0; it < 2; ++it)
      #pragma unroll
      for (int ht = 0; ht < 4; ++ht)
        *(f32x4*)&obuf[(a * 64 + 16 * ht + nid) * OBS + 16 * it + 4 * qid] = o[it][ht];
  }
  __syncthreads();
  if (c == 0) {
    float inv[2][4];
    #pragma unroll
    for (int it = 0; it < 2; ++it)
      #pragma unroll
      for (int r = 0; r < 4; ++r) {
        const int row = 32 * a + 16 * it + 4 * qid + r;
        inv[it][r] = 1.f / (lsum[row] + lsum[64 + row]);
      }
    #pragma unroll
    for (int it = 0; it < 2; ++it) {
      #pragma unroll
      for (int ht = 0; ht < 4; ++ht) {
        f32x4 oo = o[it][ht] +
                   *(const f32x4*)&obuf[(a * 64 + 16 * ht + nid) * OBS + 16 * it + 4 * qid];
        #pragma unroll
        for (int r = 0; r < 4; ++r) {
          const int row = 32 * a + 16 * it + 4 * qid + r;
          O[((size_t)b * M_ + m0 + row) * H_ + 16 * ht + nid] = oo[r] * inv[it][r];
        }
      }
    }
  }
}

extern "C" void kernel_launch(void* const* d_in, const int* in_sizes, int n_in,
                              void* d_out, int out_size, void* d_ws, size_t ws_size,
                              hipStream_t stream) {
  const float* Q  = (const float*)d_in[0];   // B x M x H
  const float* K  = (const float*)d_in[1];   // B x (M+L) x H
  const float* V  = (const float*)d_in[2];   // B x (M+L) x H
  const float* PE = (const float*)d_in[3];   // 1 x H x L
  float* O = (float*)d_out;                  // B x M x H

  dim3 grid(B_, M_ / BM);                    // batch on x: XCD-local K/V reuse
  if (d_ws != nullptr && ws_size >= PET_BYTES) {
    // init kernel runs in-graph on every launch -> robust to workspace re-poisoning
    __bf16* PET = (__bf16*)d_ws;
    hipLaunchKernelGGL(pe_pack, dim3(256), dim3(256), 0, stream, PE, PET);
    hipLaunchKernelGGL(seqattn_v9<true>, grid, dim3(256), 0, stream, Q, K, V, PE, PET, O);
  } else {
    hipLaunchKernelGGL(seqattn_v9<false>, grid, dim3(256), 0, stream, Q, K, V, PE,
                       (const __bf16*)nullptr, O);
  }
}

// Round 6
// 247.597 us; speedup vs baseline: 1.8291x; 1.1863x over previous
//
#include <hip/hip_runtime.h>
#include <math.h>

typedef __bf16 bf16x8 __attribute__((ext_vector_type(8)));
typedef __bf16 bf16x4 __attribute__((ext_vector_type(4)));
typedef float  f32x4  __attribute__((ext_vector_type(4)));
typedef short  s16x4  __attribute__((ext_vector_type(4)));

// Problem constants
constexpr int B_  = 128;
constexpr int M_  = 512;
constexpr int L_  = 1024;
constexpr int H_  = 64;
constexpr int KL_ = 1536;

// Tiling: 64 q-rows x 64 k-cols per tile; 4 waves = 2 row-halves (a) x 2 col-halves (c)
// Each block processes TWO consecutive 64-row m-tiles -> grid 512 = exactly 2 blocks/CU.
constexpr int BM  = 64;
constexpr int KT  = 64;
constexpr int NT  = 17;              // 17*64 = 1088 covers the 1024-band + 64-row skew

// LDS layout — 49152 B
constexpr int OFF_VT   = 0;          // vt[2][64][64] bf16, double-buffered, swizzled (16384 B)
constexpr int OFF_PPOS = 16384;      // ppos[64][256] bf16, swizzled (32768 B)
constexpr int SMEM_BYTES = 49152;
// epilogue overlays (after final barrier):
constexpr int OFF_OBUF = 0;          // [128][36] f32 partial O (18432 B)
constexpr int OFF_LSUM = 18432;      // [128] f32 row sums
constexpr int OBS = 36;

// PE pre-pack table: [ch(16)][nt(2)][c(2)] blocks of [lane(64)][frag f(2)][j(8)] bf16
constexpr size_t PET_BYTES = 16 * 2 * 2 * 64 * 16 * sizeof(__bf16);  // 131072

#define MFMA32(A, B, C) __builtin_amdgcn_mfma_f32_16x16x32_bf16((A), (B), (C), 0, 0, 0)

static __device__ __forceinline__ f32x4 mfma_pv(bf16x4 a, bf16x4 b, f32x4 c) {
  return __builtin_amdgcn_mfma_f32_16x16x16bf16_1k(
      __builtin_bit_cast(s16x4, a), __builtin_bit_cast(s16x4, b), c, 0, 0, 0);
}

// exp((s+pe)/8) = exp2((s+pe) * 0.125*log2(e))
constexpr float EXP2_SCALE = 0.18033688011112042f;

// 4-bit granule XOR swizzles (proven: conflicts 8.8M -> 3.5M). Row stride === 0 mod 128B,
// XOR the 8B-granule index (col bits 2..5) with (row&15); all accesses stay 4-aligned.
static __device__ __forceinline__ int vt_idx(int hrow, int kv) {   // kv in [0,64)
  return hrow * 64 + (kv ^ ((hrow & 15) << 2));
}
static __device__ __forceinline__ int pp_idx(int row, int col) {   // col in [0,256)
  return row * 256 + (col ^ ((row & 15) << 2));
}

// ---- init kernel: pack PE (1 x 64 x 1024 f32) into lane-fragment-ordered bf16 table ----
__global__ void pe_pack(const float* __restrict__ PE, __bf16* __restrict__ PET) {
  const int gid = blockIdx.x * 256 + threadIdx.x;   // 65536 = one bf16 each
  const int j   = gid & 7;
  const int f   = (gid >> 3) & 1;
  const int ln  = (gid >> 4) & 63;
  const int blk = gid >> 10;                        // = ch*4 + nt*2 + c
  const int c   = blk & 1;
  const int nt  = (blk >> 1) & 1;
  const int ch  = blk >> 2;
  const int nid = ln & 15, qid = ln >> 4;
  const int h = 8 * qid + j + 32 * f;
  const int l = 64 * ch + 32 * c + 16 * nt + nid;
  PET[gid] = (__bf16)PE[h * L_ + l];
}

template <bool USE_PET>
__global__ __launch_bounds__(256, 2)
void seqattn_v10(const float* __restrict__ Q, const float* __restrict__ K,
                 const float* __restrict__ V, const float* __restrict__ PE,
                 const __bf16* __restrict__ PET, float* __restrict__ O) {
  __shared__ alignas(16) char smem[SMEM_BYTES];
  __bf16* vtb  = (__bf16*)(smem + OFF_VT);
  __bf16* ppos = (__bf16*)(smem + OFF_PPOS);

  const int tid  = threadIdx.x;
  const int w    = tid >> 6;
  const int lane = tid & 63;
  const int nid  = lane & 15;
  const int qid  = lane >> 4;
  const int a    = w >> 1;            // q-rows 32a..32a+31
  const int c    = w & 1;             // tile cols 32c..32c+31
  const int b    = blockIdx.x;        // batch on x -> same-batch blocks share an XCD

  const int vj = (tid & 15) * 4, vh = (tid >> 4) * 4; // V staging: 4x4 reg transpose

  // fallback PE gather base (USE_PET=false only)
  const float* peg = &PE[(size_t)(8 * qid) * L_ + 32 * c + nid];

  for (int mt = 0; mt < 2; ++mt) {
    const int m0 = blockIdx.y * (2 * BM) + mt * BM;

    // protect smem reuse across m-tiles (epilogue reads of obuf/lsum done before
    // the next prologue overwrites vt/ppos). Harmless extra barrier at mt=0.
    __syncthreads();

    // ---- Q fragments (MFMA *B* operand after the operand swap) ----
    bf16x8 aq[2][2];
    #pragma unroll
    for (int it = 0; it < 2; ++it) {
      const float* qg = &Q[((size_t)b * M_ + m0 + 32 * a + 16 * it + nid) * H_];
      #pragma unroll
      for (int j = 0; j < 8; ++j) {
        aq[it][0][j] = (__bf16)qg[8 * qid + j];
        aq[it][1][j] = (__bf16)qg[32 + 8 * qid + j];
      }
    }

    f32x4 o[2][4];
    float lpart[2] = {0.f, 0.f};
    #pragma unroll
    for (int it = 0; it < 2; ++it)
      #pragma unroll
      for (int ht = 0; ht < 4; ++ht) o[it][ht] = (f32x4){0.f, 0.f, 0.f, 0.f};

    // ---------------- prologue ----------------
    // K tile 0 A-frags straight from global
    bf16x8 ak[2][2];
    #pragma unroll
    for (int nt = 0; nt < 2; ++nt) {
      const float* kg = &K[((size_t)b * KL_ + m0 + 32 * c + 16 * nt + nid) * H_ + 8 * qid];
      const f32x4 k0 = *(const f32x4*)kg;
      const f32x4 k1 = *(const f32x4*)(kg + 4);
      const f32x4 k2 = *(const f32x4*)(kg + 32);
      const f32x4 k3 = *(const f32x4*)(kg + 36);
      #pragma unroll
      for (int j = 0; j < 4; ++j) {
        ak[nt][0][j] = (__bf16)k0[j]; ak[nt][0][4 + j] = (__bf16)k1[j];
        ak[nt][1][j] = (__bf16)k2[j]; ak[nt][1][4 + j] = (__bf16)k3[j];
      }
    }
    // V tile 0
    f32x4 vr[4];
    {
      const float* vg = &V[((size_t)b * KL_ + m0 + vj) * H_ + vh];
      #pragma unroll
      for (int e = 0; e < 4; ++e) vr[e] = *(const f32x4*)(vg + e * H_);
    }
    // QPE chunk 0 -> ppos (skewed: col = (l+row)&255)
    {
      const f32x4 z = {0.f, 0.f, 0.f, 0.f};
      bf16x8 pf0[2], pf1[2];
      if constexpr (USE_PET) {
        const __bf16* pb = PET + (size_t)c * 1024 + (size_t)lane * 16;  // ch=0
        pf0[0] = *(const bf16x8*)pb;          pf1[0] = *(const bf16x8*)(pb + 8);
        pf0[1] = *(const bf16x8*)(pb + 2048); pf1[1] = *(const bf16x8*)(pb + 2048 + 8);
      } else {
        #pragma unroll
        for (int nt = 0; nt < 2; ++nt)
          #pragma unroll
          for (int j = 0; j < 8; ++j) {
            pf0[nt][j] = (__bf16)peg[(size_t)j * L_ + 16 * nt];
            pf1[nt][j] = (__bf16)peg[(size_t)(32 + j) * L_ + 16 * nt];
          }
      }
      #pragma unroll
      for (int nt = 0; nt < 2; ++nt) {
        #pragma unroll
        for (int it = 0; it < 2; ++it) {
          f32x4 pp = MFMA32(pf0[nt], aq[it][0], z);
          pp = MFMA32(pf1[nt], aq[it][1], pp);
          const int row = 32 * a + 16 * it + nid;
          const int cb  = 32 * c + 16 * nt + 4 * qid + row;   // ch=0: l + row
          #pragma unroll
          for (int r = 0; r < 4; ++r)
            ppos[pp_idx(row, (cb + r) & 255)] = (__bf16)pp[r];
        }
      }
    }
    // stage V tile 0 -> buf 0
    #pragma unroll
    for (int e = 0; e < 4; ++e) {
      bf16x4 y = {(__bf16)vr[0][e], (__bf16)vr[1][e], (__bf16)vr[2][e], (__bf16)vr[3][e]};
      *(bf16x4*)&vtb[vt_idx(vh + e, vj)] = y;
    }
    __syncthreads();

    // ---------------- main loop: ONE barrier per tile (double-buffered vt) ----------------
    for (int t = 0; t < NT; ++t) {
      // A: ppos reads for this tile (slot t&3; aligned b64; swizzled)
      bf16x4 pe4[2][2];
      #pragma unroll
      for (int it = 0; it < 2; ++it) {
        const int row = 32 * a + 16 * it + nid;
        #pragma unroll
        for (int nt = 0; nt < 2; ++nt)
          pe4[it][nt] = *(const bf16x4*)
              &ppos[pp_idx(row, 64 * (t & 3) + 32 * c + 16 * nt + 4 * qid)];
      }

      // A2: PET loads for chunk t+1 (2x16B coalesced, L2-resident)
      bf16x8 pf0[2], pf1[2];
      if (t < 15) {
        if constexpr (USE_PET) {
          const __bf16* pb = PET + ((size_t)(t + 1) * 4 + c) * 1024 + (size_t)lane * 16;
          pf0[0] = *(const bf16x8*)pb;          pf1[0] = *(const bf16x8*)(pb + 8);
          pf0[1] = *(const bf16x8*)(pb + 2048); pf1[1] = *(const bf16x8*)(pb + 2048 + 8);
        } else {
          const float* pc = peg + (t + 1) * 64;
          #pragma unroll
          for (int nt = 0; nt < 2; ++nt)
            #pragma unroll
            for (int j = 0; j < 8; ++j) {
              pf0[nt][j] = (__bf16)pc[(size_t)j * L_ + 16 * nt];
              pf1[nt][j] = (__bf16)pc[(size_t)(32 + j) * L_ + 16 * nt];
            }
        }
      }

      // B: prefetch V tile t+1 into registers (consumed at G; issued early for latency)
      if (t < 16) {
        const float* vg = &V[((size_t)b * KL_ + m0 + KT * (t + 1) + vj) * H_ + vh];
        #pragma unroll
        for (int e = 0; e < 4; ++e) vr[e] = *(const f32x4*)(vg + e * H_);
      }

      const __bf16* vtt = vtb + (t & 1) * 64 * 64;
      const f32x4 z = {0.f, 0.f, 0.f, 0.f};

      // C: QK^T swapped: S^T = mfma(A=K, B=Q); lane(nid,qid) reg r ->
      //    S[qrow=32a+16it+nid][kcol=64t+32c+16nt+4qid+r]
      f32x4 s[2][2];
      #pragma unroll
      for (int nt = 0; nt < 2; ++nt)
        #pragma unroll
        for (int it = 0; it < 2; ++it) {
          s[it][nt] = MFMA32(ak[nt][0], aq[it][0], z);
          s[it][nt] = MFMA32(ak[nt][1], aq[it][1], s[it][nt]);
        }

      // B2: reload K tile t+1 directly into ak (consumed next iter at C) — no akn copy
      if (t < 16) {
        const int j1 = m0 + KT * (t + 1);
        #pragma unroll
        for (int nt = 0; nt < 2; ++nt) {
          const float* kg = &K[((size_t)b * KL_ + j1 + 32 * c + 16 * nt + nid) * H_ + 8 * qid];
          const f32x4 k0 = *(const f32x4*)kg;
          const f32x4 k1 = *(const f32x4*)(kg + 4);
          const f32x4 k2 = *(const f32x4*)(kg + 32);
          const f32x4 k3 = *(const f32x4*)(kg + 36);
          #pragma unroll
          for (int j = 0; j < 4; ++j) {
            ak[nt][0][j] = (__bf16)k0[j]; ak[nt][0][4 + j] = (__bf16)k1[j];
            ak[nt][1][j] = (__bf16)k2[j]; ak[nt][1][4 + j] = (__bf16)k3[j];
          }
        }
      }

      // D: QPE chunk t+1 -> skewed stores (slots (t+1..t+3)&3; never slot t&3)
      if (t < 15) {
        const int chb = 64 * (t + 1);
        #pragma unroll
        for (int nt = 0; nt < 2; ++nt) {
          #pragma unroll
          for (int it = 0; it < 2; ++it) {
            f32x4 pp = MFMA32(pf0[nt], aq[it][0], z);
            pp = MFMA32(pf1[nt], aq[it][1], pp);
            const int row = 32 * a + 16 * it + nid;
            const int cb  = chb + 32 * c + 16 * nt + 4 * qid + row;
            #pragma unroll
            for (int r = 0; r < 4; ++r)
              ppos[pp_idx(row, (cb + r) & 255)] = (__bf16)pp[r];
          }
        }
      }

      // E: softmax: exp in-register, build PV A-frags
      const bool edge = (t == 0) || (t == 16);
      bf16x4 pa[2][2];
      #pragma unroll
      for (int it = 0; it < 2; ++it) {
        const int row = 32 * a + 16 * it + nid;
        #pragma unroll
        for (int nt = 0; nt < 2; ++nt) {
          const int lb = KT * t + 32 * c + 16 * nt + 4 * qid - row;
          #pragma unroll
          for (int r = 0; r < 4; ++r) {
            const int l = lb + r;
            float p;
            if (!edge || (unsigned)l < 1024u)
              p = exp2f((s[it][nt][r] + (float)pe4[it][nt][r]) * EXP2_SCALE);
            else
              p = 0.f;
            lpart[it] += p;
            pa[it][nt][r] = (__bf16)p;
          }
        }
      }

      // F: PV: 16x16x16, A = pa (regs), B = V^T from LDS (swizzled)
      #pragma unroll
      for (int nt = 0; nt < 2; ++nt) {
        bf16x4 vb[4];
        #pragma unroll
        for (int ht = 0; ht < 4; ++ht)
          vb[ht] = *(const bf16x4*)&vtt[vt_idx(16 * ht + nid, 32 * c + 16 * nt + 4 * qid)];
        #pragma unroll
        for (int it = 0; it < 2; ++it)
          #pragma unroll
          for (int ht = 0; ht < 4; ++ht)
            o[it][ht] = mfma_pv(pa[it][nt], vb[ht], o[it][ht]);
      }

      // G: stage prefetched V tile t+1 into the other buffer
      if (t < 16) {
        __bf16* vtn = vtb + ((t + 1) & 1) * 64 * 64;
        #pragma unroll
        for (int e = 0; e < 4; ++e) {
          bf16x4 y = {(__bf16)vr[0][e], (__bf16)vr[1][e], (__bf16)vr[2][e], (__bf16)vr[3][e]};
          *(bf16x4*)&vtn[vt_idx(vh + e, vj)] = y;
        }
      }
      __syncthreads();
    }

    // ---------------- epilogue: merge c-halves, normalize, store ----------------
    float* lsum = (float*)(smem + OFF_LSUM);
    float* obuf = (float*)(smem + OFF_OBUF);

    #pragma unroll
    for (int it = 0; it < 2; ++it) {
      float v = lpart[it];
      v += __shfl_xor(v, 16);
      v += __shfl_xor(v, 32);
      lpart[it] = v;
    }
    if (qid == 0) {
      #pragma unroll
      for (int it = 0; it < 2; ++it)
        lsum[c * 64 + 32 * a + 16 * it + nid] = lpart[it];
    }
    if (c == 1) {
      #pragma unroll
      for (int it = 0; it < 2; ++it)
        #pragma unroll
        for (int ht = 0; ht < 4; ++ht)
          *(f32x4*)&obuf[(a * 64 + 16 * ht + nid) * OBS + 16 * it + 4 * qid] = o[it][ht];
    }
    __syncthreads();
    if (c == 0) {
      float inv[2][4];
      #pragma unroll
      for (int it = 0; it < 2; ++it)
        #pragma unroll
        for (int r = 0; r < 4; ++r) {
          const int row = 32 * a + 16 * it + 4 * qid + r;
          inv[it][r] = 1.f / (lsum[row] + lsum[64 + row]);
        }
      #pragma unroll
      for (int it = 0; it < 2; ++it) {
        #pragma unroll
        for (int ht = 0; ht < 4; ++ht) {
          f32x4 oo = o[it][ht] +
                     *(const f32x4*)&obuf[(a * 64 + 16 * ht + nid) * OBS + 16 * it + 4 * qid];
          #pragma unroll
          for (int r = 0; r < 4; ++r) {
            const int row = 32 * a + 16 * it + 4 * qid + r;
            O[((size_t)b * M_ + m0 + row) * H_ + 16 * ht + nid] = oo[r] * inv[it][r];
          }
        }
      }
    }
  }
}

extern "C" void kernel_launch(void* const* d_in, const int* in_sizes, int n_in,
                              void* d_out, int out_size, void* d_ws, size_t ws_size,
                              hipStream_t stream) {
  const float* Q  = (const float*)d_in[0];   // B x M x H
  const float* K  = (const float*)d_in[1];   // B x (M+L) x H
  const float* V  = (const float*)d_in[2];   // B x (M+L) x H
  const float* PE = (const float*)d_in[3];   // 1 x H x L
  float* O = (float*)d_out;                  // B x M x H

  dim3 grid(B_, M_ / (2 * BM));              // 512 blocks = exactly 2/CU, single phase
  if (d_ws != nullptr && ws_size >= PET_BYTES) {
    // init kernel runs in-graph on every launch -> robust to workspace re-poisoning
    __bf16* PET = (__bf16*)d_ws;
    hipLaunchKernelGGL(pe_pack, dim3(256), dim3(256), 0, stream, PE, PET);
    hipLaunchKernelGGL(seqattn_v10<true>, grid, dim3(256), 0, stream, Q, K, V, PE, PET, O);
  } else {
    hipLaunchKernelGGL(seqattn_v10<false>, grid, dim3(256), 0, stream, Q, K, V, PE,
                       (const __bf16*)nullptr, O);
  }
}

// Round 7
// 226.198 us; speedup vs baseline: 2.0021x; 1.0946x over previous
//
#include <hip/hip_runtime.h>
#include <math.h>

typedef __bf16 bf16x8 __attribute__((ext_vector_type(8)));
typedef __bf16 bf16x4 __attribute__((ext_vector_type(4)));
typedef float  f32x4  __attribute__((ext_vector_type(4)));
typedef short  s16x4  __attribute__((ext_vector_type(4)));

// Problem constants
constexpr int B_  = 128;
constexpr int M_  = 512;
constexpr int L_  = 1024;
constexpr int H_  = 64;
constexpr int KL_ = 1536;

// Tiling: 64 q-rows x 64 k-cols per tile; 4 waves = 2 row-halves (a) x 2 col-halves (c)
constexpr int BM  = 64;
constexpr int KT  = 64;
constexpr int NT  = 17;              // 17*64 = 1088 covers the 1024-band + 64-row skew
constexpr int PPC = 192;             // ppos cols: 3 rolling 64-wide chunks (mod-192 skew)

// LDS layout — exactly 40960 B -> 4 blocks/CU at 160 KiB (v8-proven residency),
// combined with the v10-proven no-spill codegen (launch_bounds(256,2)) and a
// 1024-block grid = exactly 4/CU single phase.
constexpr int OFF_VT   = 0;          // vt[2][64][64] bf16, double-buffered, swizzled (16384 B)
constexpr int OFF_PPOS = 16384;      // ppos[64][192] bf16, 3-slot rolling, swizzled (24576 B)
constexpr int SMEM_BYTES = 40960;
// epilogue overlays (after final barrier):
constexpr int OFF_OBUF = 0;          // [128][36] f32 partial O (18432 B)
constexpr int OFF_LSUM = 18432;      // [128] f32 row sums
constexpr int OBS = 36;

// PE pre-pack table: [ch(16)][nt(2)][c(2)] blocks of [lane(64)][frag f(2)][j(8)] bf16
constexpr size_t PET_BYTES = 16 * 2 * 2 * 64 * 16 * sizeof(__bf16);  // 131072

#define MFMA32(A, B, C) __builtin_amdgcn_mfma_f32_16x16x32_bf16((A), (B), (C), 0, 0, 0)

static __device__ __forceinline__ f32x4 mfma_pv(bf16x4 a, bf16x4 b, f32x4 c) {
  return __builtin_amdgcn_mfma_f32_16x16x16bf16_1k(
      __builtin_bit_cast(s16x4, a), __builtin_bit_cast(s16x4, b), c, 0, 0, 0);
}

// exp((s+pe)/8) = exp2((s+pe) * 0.125*log2(e))
constexpr float EXP2_SCALE = 0.18033688011112042f;

// 4-bit granule XOR swizzles (proven: conflicts 8.8M -> 3.5M). Row strides are
// === 0 mod 128B, so XOR the 8B-granule index (col bits 2..5) with (row&15).
// ppos has 48 granules/row; XOR of the low 4 granule bits keeps g in [0,48) (bijective).
static __device__ __forceinline__ int vt_idx(int hrow, int kv) {   // kv in [0,64)
  return hrow * 64 + (kv ^ ((hrow & 15) << 2));
}
static __device__ __forceinline__ int pp_idx(int row, int col) {   // col in [0,192)
  return row * PPC + (col ^ ((row & 15) << 2));
}

// ---- init kernel: pack PE (1 x 64 x 1024 f32) into lane-fragment-ordered bf16 table ----
__global__ void pe_pack(const float* __restrict__ PE, __bf16* __restrict__ PET) {
  const int gid = blockIdx.x * 256 + threadIdx.x;   // 65536 = one bf16 each
  const int j   = gid & 7;
  const int f   = (gid >> 3) & 1;
  const int ln  = (gid >> 4) & 63;
  const int blk = gid >> 10;                        // = ch*4 + nt*2 + c
  const int c   = blk & 1;
  const int nt  = (blk >> 1) & 1;
  const int ch  = blk >> 2;
  const int nid = ln & 15, qid = ln >> 4;
  const int h = 8 * qid + j + 32 * f;
  const int l = 64 * ch + 32 * c + 16 * nt + nid;
  PET[gid] = (__bf16)PE[h * L_ + l];
}

template <bool USE_PET>
__global__ __launch_bounds__(256, 2)
void seqattn_v11(const float* __restrict__ Q, const float* __restrict__ K,
                 const float* __restrict__ V, const float* __restrict__ PE,
                 const __bf16* __restrict__ PET, float* __restrict__ O) {
  __shared__ alignas(16) char smem[SMEM_BYTES];
  __bf16* vtb  = (__bf16*)(smem + OFF_VT);
  __bf16* ppos = (__bf16*)(smem + OFF_PPOS);

  const int tid  = threadIdx.x;
  const int w    = tid >> 6;
  const int lane = tid & 63;
  const int nid  = lane & 15;
  const int qid  = lane >> 4;
  const int a    = w >> 1;            // q-rows 32a..32a+31
  const int c    = w & 1;             // tile cols 32c..32c+31
  const int b    = blockIdx.x;        // batch on x -> same-batch blocks share an XCD
  const int m0   = blockIdx.y * BM;

  const int vj = (tid & 15) * 4, vh = (tid >> 4) * 4; // V staging: 4x4 reg transpose

  // fallback PE gather base (USE_PET=false only)
  const float* peg = &PE[(size_t)(8 * qid) * L_ + 32 * c + nid];

  // ---- Q fragments (MFMA *B* operand after the operand swap) ----
  bf16x8 aq[2][2];
  #pragma unroll
  for (int it = 0; it < 2; ++it) {
    const float* qg = &Q[((size_t)b * M_ + m0 + 32 * a + 16 * it + nid) * H_];
    #pragma unroll
    for (int j = 0; j < 8; ++j) {
      aq[it][0][j] = (__bf16)qg[8 * qid + j];
      aq[it][1][j] = (__bf16)qg[32 + 8 * qid + j];
    }
  }

  f32x4 o[2][4];
  float lpart[2] = {0.f, 0.f};
  #pragma unroll
  for (int it = 0; it < 2; ++it)
    #pragma unroll
    for (int ht = 0; ht < 4; ++ht) o[it][ht] = (f32x4){0.f, 0.f, 0.f, 0.f};

  // ---------------- prologue ----------------
  // K tile 0 A-frags straight from global
  bf16x8 ak[2][2];
  #pragma unroll
  for (int nt = 0; nt < 2; ++nt) {
    const float* kg = &K[((size_t)b * KL_ + m0 + 32 * c + 16 * nt + nid) * H_ + 8 * qid];
    const f32x4 k0 = *(const f32x4*)kg;
    const f32x4 k1 = *(const f32x4*)(kg + 4);
    const f32x4 k2 = *(const f32x4*)(kg + 32);
    const f32x4 k3 = *(const f32x4*)(kg + 36);
    #pragma unroll
    for (int j = 0; j < 4; ++j) {
      ak[nt][0][j] = (__bf16)k0[j]; ak[nt][0][4 + j] = (__bf16)k1[j];
      ak[nt][1][j] = (__bf16)k2[j]; ak[nt][1][4 + j] = (__bf16)k3[j];
    }
  }
  // V tile 0
  f32x4 vr[4];
  {
    const float* vg = &V[((size_t)b * KL_ + m0 + vj) * H_ + vh];
    #pragma unroll
    for (int e = 0; e < 4; ++e) vr[e] = *(const f32x4*)(vg + e * H_);
  }
  // QPE chunk 0 -> ppos (skewed: col = (l+row) mod 192)
  {
    const f32x4 z = {0.f, 0.f, 0.f, 0.f};
    bf16x8 pf0[2], pf1[2];
    if constexpr (USE_PET) {
      const __bf16* pb = PET + (size_t)c * 1024 + (size_t)lane * 16;  // ch=0
      pf0[0] = *(const bf16x8*)pb;          pf1[0] = *(const bf16x8*)(pb + 8);
      pf0[1] = *(const bf16x8*)(pb + 2048); pf1[1] = *(const bf16x8*)(pb + 2048 + 8);
    } else {
      #pragma unroll
      for (int nt = 0; nt < 2; ++nt)
        #pragma unroll
        for (int j = 0; j < 8; ++j) {
          pf0[nt][j] = (__bf16)peg[(size_t)j * L_ + 16 * nt];
          pf1[nt][j] = (__bf16)peg[(size_t)(32 + j) * L_ + 16 * nt];
        }
    }
    #pragma unroll
    for (int nt = 0; nt < 2; ++nt) {
      #pragma unroll
      for (int it = 0; it < 2; ++it) {
        f32x4 pp = MFMA32(pf0[nt], aq[it][0], z);
        pp = MFMA32(pf1[nt], aq[it][1], pp);
        const int row = 32 * a + 16 * it + nid;
        const int cb  = 32 * c + 16 * nt + 4 * qid + row;   // ch=0: l + row
        #pragma unroll
        for (int r = 0; r < 4; ++r)
          ppos[pp_idx(row, (cb + r) % PPC)] = (__bf16)pp[r];
      }
    }
  }
  // stage V tile 0 -> buf 0
  #pragma unroll
  for (int e = 0; e < 4; ++e) {
    bf16x4 y = {(__bf16)vr[0][e], (__bf16)vr[1][e], (__bf16)vr[2][e], (__bf16)vr[3][e]};
    *(bf16x4*)&vtb[vt_idx(vh + e, vj)] = y;
  }
  __syncthreads();

  // ---------------- main loop: ONE barrier per tile (double-buffered vt) ----------------
  for (int t = 0; t < NT; ++t) {
    // A: ppos reads for this tile (slot t%3; aligned b64; swizzled)
    bf16x4 pe4[2][2];
    #pragma unroll
    for (int it = 0; it < 2; ++it) {
      const int row = 32 * a + 16 * it + nid;
      #pragma unroll
      for (int nt = 0; nt < 2; ++nt)
        pe4[it][nt] = *(const bf16x4*)
            &ppos[pp_idx(row, 64 * (t % 3) + 32 * c + 16 * nt + 4 * qid)];
    }

    // A2: PET loads for chunk t+1 (2x16B coalesced, L2-resident)
    bf16x8 pf0[2], pf1[2];
    if (t < 15) {
      if constexpr (USE_PET) {
        const __bf16* pb = PET + ((size_t)(t + 1) * 4 + c) * 1024 + (size_t)lane * 16;
        pf0[0] = *(const bf16x8*)pb;          pf1[0] = *(const bf16x8*)(pb + 8);
        pf0[1] = *(const bf16x8*)(pb + 2048); pf1[1] = *(const bf16x8*)(pb + 2048 + 8);
      } else {
        const float* pc = peg + (t + 1) * 64;
        #pragma unroll
        for (int nt = 0; nt < 2; ++nt)
          #pragma unroll
          for (int j = 0; j < 8; ++j) {
            pf0[nt][j] = (__bf16)pc[(size_t)j * L_ + 16 * nt];
            pf1[nt][j] = (__bf16)pc[(size_t)(32 + j) * L_ + 16 * nt];
          }
      }
    }

    // B: prefetch V tile t+1 into registers (consumed at G)
    if (t < 16) {
      const float* vg = &V[((size_t)b * KL_ + m0 + KT * (t + 1) + vj) * H_ + vh];
      #pragma unroll
      for (int e = 0; e < 4; ++e) vr[e] = *(const f32x4*)(vg + e * H_);
    }

    const __bf16* vtt = vtb + (t & 1) * 64 * 64;
    const f32x4 z = {0.f, 0.f, 0.f, 0.f};

    // C: QK^T swapped: S^T = mfma(A=K, B=Q); lane(nid,qid) reg r ->
    //    S[qrow=32a+16it+nid][kcol=64t+32c+16nt+4qid+r]
    f32x4 s[2][2];
    #pragma unroll
    for (int nt = 0; nt < 2; ++nt)
      #pragma unroll
      for (int it = 0; it < 2; ++it) {
        s[it][nt] = MFMA32(ak[nt][0], aq[it][0], z);
        s[it][nt] = MFMA32(ak[nt][1], aq[it][1], s[it][nt]);
      }

    // B2: reload K tile t+1 directly into ak (consumed next iter at C)
    if (t < 16) {
      const int j1 = m0 + KT * (t + 1);
      #pragma unroll
      for (int nt = 0; nt < 2; ++nt) {
        const float* kg = &K[((size_t)b * KL_ + j1 + 32 * c + 16 * nt + nid) * H_ + 8 * qid];
        const f32x4 k0 = *(const f32x4*)kg;
        const f32x4 k1 = *(const f32x4*)(kg + 4);
        const f32x4 k2 = *(const f32x4*)(kg + 32);
        const f32x4 k3 = *(const f32x4*)(kg + 36);
        #pragma unroll
        for (int j = 0; j < 4; ++j) {
          ak[nt][0][j] = (__bf16)k0[j]; ak[nt][0][4 + j] = (__bf16)k1[j];
          ak[nt][1][j] = (__bf16)k2[j]; ak[nt][1][4 + j] = (__bf16)k3[j];
        }
      }
    }

    // D: QPE chunk t+1 -> skewed stores (slots (t+1)%3,(t+2)%3; never the read slot t%3)
    if (t < 15) {
      const int chb = 64 * (t + 1);
      #pragma unroll
      for (int nt = 0; nt < 2; ++nt) {
        #pragma unroll
        for (int it = 0; it < 2; ++it) {
          f32x4 pp = MFMA32(pf0[nt], aq[it][0], z);
          pp = MFMA32(pf1[nt], aq[it][1], pp);
          const int row = 32 * a + 16 * it + nid;
          const int cb  = chb + 32 * c + 16 * nt + 4 * qid + row;
          #pragma unroll
          for (int r = 0; r < 4; ++r)
            ppos[pp_idx(row, (cb + r) % PPC)] = (__bf16)pp[r];
        }
      }
    }

    // E: softmax: exp in-register, build PV A-frags
    const bool edge = (t == 0) || (t == 16);
    bf16x4 pa[2][2];
    #pragma unroll
    for (int it = 0; it < 2; ++it) {
      const int row = 32 * a + 16 * it + nid;
      #pragma unroll
      for (int nt = 0; nt < 2; ++nt) {
        const int lb = KT * t + 32 * c + 16 * nt + 4 * qid - row;
        #pragma unroll
        for (int r = 0; r < 4; ++r) {
          const int l = lb + r;
          float p;
          if (!edge || (unsigned)l < 1024u)
            p = exp2f((s[it][nt][r] + (float)pe4[it][nt][r]) * EXP2_SCALE);
          else
            p = 0.f;
          lpart[it] += p;
          pa[it][nt][r] = (__bf16)p;
        }
      }
    }

    // F: PV: 16x16x16, A = pa (regs), B = V^T from LDS (swizzled)
    #pragma unroll
    for (int nt = 0; nt < 2; ++nt) {
      bf16x4 vb[4];
      #pragma unroll
      for (int ht = 0; ht < 4; ++ht)
        vb[ht] = *(const bf16x4*)&vtt[vt_idx(16 * ht + nid, 32 * c + 16 * nt + 4 * qid)];
      #pragma unroll
      for (int it = 0; it < 2; ++it)
        #pragma unroll
        for (int ht = 0; ht < 4; ++ht)
          o[it][ht] = mfma_pv(pa[it][nt], vb[ht], o[it][ht]);
    }

    // G: stage prefetched V tile t+1 into the other buffer
    if (t < 16) {
      __bf16* vtn = vtb + ((t + 1) & 1) * 64 * 64;
      #pragma unroll
      for (int e = 0; e < 4; ++e) {
        bf16x4 y = {(__bf16)vr[0][e], (__bf16)vr[1][e], (__bf16)vr[2][e], (__bf16)vr[3][e]};
        *(bf16x4*)&vtn[vt_idx(vh + e, vj)] = y;
      }
    }
    __syncthreads();
  }

  // ---------------- epilogue: merge c-halves, normalize, store ----------------
  float* lsum = (float*)(smem + OFF_LSUM);
  float* obuf = (float*)(smem + OFF_OBUF);

  #pragma unroll
  for (int it = 0; it < 2; ++it) {
    float v = lpart[it];
    v += __shfl_xor(v, 16);
    v += __shfl_xor(v, 32);
    lpart[it] = v;
  }
  if (qid == 0) {
    #pragma unroll
    for (int it = 0; it < 2; ++it)
      lsum[c * 64 + 32 * a + 16 * it + nid] = lpart[it];
  }
  if (c == 1) {
    #pragma unroll
    for (int it = 0; it < 2; ++it)
      #pragma unroll
      for (int ht = 0; ht < 4; ++ht)
        *(f32x4*)&obuf[(a * 64 + 16 * ht + nid) * OBS + 16 * it + 4 * qid] = o[it][ht];
  }
  __syncthreads();
  if (c == 0) {
    float inv[2][4];
    #pragma unroll
    for (int it = 0; it < 2; ++it)
      #pragma unroll
      for (int r = 0; r < 4; ++r) {
        const int row = 32 * a + 16 * it + 4 * qid + r;
        inv[it][r] = 1.f / (lsum[row] + lsum[64 + row]);
      }
    #pragma unroll
    for (int it = 0; it < 2; ++it) {
      #pragma unroll
      for (int ht = 0; ht < 4; ++ht) {
        f32x4 oo = o[it][ht] +
                   *(const f32x4*)&obuf[(a * 64 + 16 * ht + nid) * OBS + 16 * it + 4 * qid];
        #pragma unroll
        for (int r = 0; r < 4; ++r) {
          const int row = 32 * a + 16 * it + 4 * qid + r;
          O[((size_t)b * M_ + m0 + row) * H_ + 16 * ht + nid] = oo[r] * inv[it][r];
        }
      }
    }
  }
}

extern "C" void kernel_launch(void* const* d_in, const int* in_sizes, int n_in,
                              void* d_out, int out_size, void* d_ws, size_t ws_size,
                              hipStream_t stream) {
  const float* Q  = (const float*)d_in[0];   // B x M x H
  const float* K  = (const float*)d_in[1];   // B x (M+L) x H
  const float* V  = (const float*)d_in[2];   // B x (M+L) x H
  const float* PE = (const float*)d_in[3];   // 1 x H x L
  float* O = (float*)d_out;                  // B x M x H

  dim3 grid(B_, M_ / BM);                    // 1024 blocks = exactly 4/CU, single phase
  if (d_ws != nullptr && ws_size >= PET_BYTES) {
    // init kernel runs in-graph on every launch -> robust to workspace re-poisoning
    __bf16* PET = (__bf16*)d_ws;
    hipLaunchKernelGGL(pe_pack, dim3(256), dim3(256), 0, stream, PE, PET);
    hipLaunchKernelGGL(seqattn_v11<true>, grid, dim3(256), 0, stream, Q, K, V, PE, PET, O);
  } else {
    hipLaunchKernelGGL(seqattn_v11<false>, grid, dim3(256), 0, stream, Q, K, V, PE,
                       (const __bf16*)nullptr, O);
  }
}

// Round 8
// 224.728 us; speedup vs baseline: 2.0152x; 1.0065x over previous
//
#include <hip/hip_runtime.h>
#include <math.h>

typedef __bf16 bf16x8 __attribute__((ext_vector_type(8)));
typedef __bf16 bf16x4 __attribute__((ext_vector_type(4)));
typedef float  f32x4  __attribute__((ext_vector_type(4)));
typedef short  s16x4  __attribute__((ext_vector_type(4)));

// Problem constants
constexpr int B_  = 128;
constexpr int M_  = 512;
constexpr int L_  = 1024;
constexpr int H_  = 64;
constexpr int KL_ = 1536;

// Tiling: 64 q-rows x 64 k-cols per tile; 4 waves.
// Region A (QK/softmax): wave = (a = q-row half, c = k-col half)
// Region B (PV):         wave = (a = q-row half, d = h half), all 64 kv
constexpr int BM  = 64;
constexpr int KT  = 64;
constexpr int NT  = 17;              // 17*64 = 1088 covers the 1024-band + 64-row skew
constexpr int PPC = 192;             // ppos cols: 3 rolling 64-wide chunks (mod-192 skew)

// LDS — exactly 40960 B -> 4 blocks/CU at 160 KiB; total VGPR target <=128 -> 4 waves/SIMD
constexpr int OFF_VT   = 0;          // vt[64][64] bf16, single-buffered, swizzled (8192 B)
constexpr int OFF_P    = 8192;       // P[64][64] bf16, single-buffered, swizzled (8192 B)
constexpr int OFF_PPOS = 16384;      // ppos[64][192] bf16, 3-slot rolling, swizzled (24576 B)
constexpr int SMEM_BYTES = 40960;
constexpr int OFF_LSUM = 16384;      // epilogue overlay over ppos: [128] f32 row sums

// PE pre-pack table: [ch(16)][nt(2)][c(2)] blocks of [lane(64)][frag f(2)][j(8)] bf16
constexpr size_t PET_BYTES = 16 * 2 * 2 * 64 * 16 * sizeof(__bf16);  // 131072

#define MFMA32(A, B, C) __builtin_amdgcn_mfma_f32_16x16x32_bf16((A), (B), (C), 0, 0, 0)

static __device__ __forceinline__ f32x4 mfma_pv(bf16x4 a, bf16x4 b, f32x4 c) {
  return __builtin_amdgcn_mfma_f32_16x16x16bf16_1k(
      __builtin_bit_cast(s16x4, a), __builtin_bit_cast(s16x4, b), c, 0, 0, 0);
}

// exp((s+pe)/8) = exp2((s+pe) * 0.125*log2(e))
constexpr float EXP2_SCALE = 0.18033688011112042f;

// 4-bit granule XOR swizzles: row strides === 0 mod 128B, XOR col bits 2..5 with row&15.
// All b64 accesses use 4-aligned col bases; every read/write pattern = 4 lanes/8B-granule.
static __device__ __forceinline__ int sw_idx(int row, int col) {   // 64-col tiles (vt, P)
  return row * 64 + (col ^ ((row & 15) << 2));
}
static __device__ __forceinline__ int pp_idx(int row, int col) {   // col in [0,192)
  return row * PPC + (col ^ ((row & 15) << 2));
}

// ---- init kernel: pack PE (1 x 64 x 1024 f32) into lane-fragment-ordered bf16 table ----
__global__ void pe_pack(const float* __restrict__ PE, __bf16* __restrict__ PET) {
  const int gid = blockIdx.x * 256 + threadIdx.x;   // 65536 = one bf16 each
  const int j   = gid & 7;
  const int f   = (gid >> 3) & 1;
  const int ln  = (gid >> 4) & 63;
  const int blk = gid >> 10;                        // = ch*4 + nt*2 + c
  const int c   = blk & 1;
  const int nt  = (blk >> 1) & 1;
  const int ch  = blk >> 2;
  const int nid = ln & 15, qid = ln >> 4;
  const int h = 8 * qid + j + 32 * f;
  const int l = 64 * ch + 32 * c + 16 * nt + nid;
  PET[gid] = (__bf16)PE[h * L_ + l];
}

template <bool USE_PET>
__global__ __launch_bounds__(256, 2)
void seqattn_v12(const float* __restrict__ Q, const float* __restrict__ K,
                 const float* __restrict__ V, const float* __restrict__ PE,
                 const __bf16* __restrict__ PET, float* __restrict__ O) {
  __shared__ alignas(16) char smem[SMEM_BYTES];
  __bf16* vtb  = (__bf16*)(smem + OFF_VT);
  __bf16* Pl   = (__bf16*)(smem + OFF_P);
  __bf16* ppos = (__bf16*)(smem + OFF_PPOS);

  const int tid  = threadIdx.x;
  const int w    = tid >> 6;
  const int lane = tid & 63;
  const int nid  = lane & 15;
  const int qid  = lane >> 4;
  const int a    = w >> 1;            // q-rows 32a..32a+31
  const int c    = w & 1;             // region A: k-col half; region B: h half (d == c)
  const int b    = blockIdx.x;        // batch on x -> same-batch blocks share an XCD
  const int m0   = blockIdx.y * BM;

  const int vj = (tid & 15) * 4, vh = (tid >> 4) * 4; // V staging: 4x4 reg transpose

  // fallback PE gather base (USE_PET=false only)
  const float* peg = &PE[(size_t)(8 * qid) * L_ + 32 * c + nid];

  // ---- Q fragments (MFMA *B* operand in the swapped QK) ----
  bf16x8 aq[2][2];
  #pragma unroll
  for (int it = 0; it < 2; ++it) {
    const float* qg = &Q[((size_t)b * M_ + m0 + 32 * a + 16 * it + nid) * H_];
    #pragma unroll
    for (int j = 0; j < 8; ++j) {
      aq[it][0][j] = (__bf16)qg[8 * qid + j];
      aq[it][1][j] = (__bf16)qg[32 + 8 * qid + j];
    }
  }

  f32x4 o[2][2];                      // o[it][ht]: rows 32a+16it+4qid+r, h = 32c+16ht+nid
  float lpart[2] = {0.f, 0.f};
  #pragma unroll
  for (int it = 0; it < 2; ++it)
    #pragma unroll
    for (int ht = 0; ht < 2; ++ht) o[it][ht] = (f32x4){0.f, 0.f, 0.f, 0.f};

  // ---------------- prologue ----------------
  // K tile 0 A-frags straight from global
  bf16x8 ak[2][2];
  #pragma unroll
  for (int nt = 0; nt < 2; ++nt) {
    const float* kg = &K[((size_t)b * KL_ + m0 + 32 * c + 16 * nt + nid) * H_ + 8 * qid];
    const f32x4 k0 = *(const f32x4*)kg;
    const f32x4 k1 = *(const f32x4*)(kg + 4);
    const f32x4 k2 = *(const f32x4*)(kg + 32);
    const f32x4 k3 = *(const f32x4*)(kg + 36);
    #pragma unroll
    for (int j = 0; j < 4; ++j) {
      ak[nt][0][j] = (__bf16)k0[j]; ak[nt][0][4 + j] = (__bf16)k1[j];
      ak[nt][1][j] = (__bf16)k2[j]; ak[nt][1][4 + j] = (__bf16)k3[j];
    }
  }
  // V tile 0 into registers
  f32x4 vr[4];
  {
    const float* vg = &V[((size_t)b * KL_ + m0 + vj) * H_ + vh];
    #pragma unroll
    for (int e = 0; e < 4; ++e) vr[e] = *(const f32x4*)(vg + e * H_);
  }
  // QPE chunk 0 -> ppos (skewed: col = (l+row) mod 192)
  {
    const f32x4 z = {0.f, 0.f, 0.f, 0.f};
    bf16x8 pf0[2], pf1[2];
    if constexpr (USE_PET) {
      const __bf16* pb = PET + (size_t)c * 1024 + (size_t)lane * 16;  // ch=0
      pf0[0] = *(const bf16x8*)pb;          pf1[0] = *(const bf16x8*)(pb + 8);
      pf0[1] = *(const bf16x8*)(pb + 2048); pf1[1] = *(const bf16x8*)(pb + 2048 + 8);
    } else {
      #pragma unroll
      for (int nt = 0; nt < 2; ++nt)
        #pragma unroll
        for (int j = 0; j < 8; ++j) {
          pf0[nt][j] = (__bf16)peg[(size_t)j * L_ + 16 * nt];
          pf1[nt][j] = (__bf16)peg[(size_t)(32 + j) * L_ + 16 * nt];
        }
    }
    #pragma unroll
    for (int nt = 0; nt < 2; ++nt) {
      #pragma unroll
      for (int it = 0; it < 2; ++it) {
        f32x4 pp = MFMA32(pf0[nt], aq[it][0], z);
        pp = MFMA32(pf1[nt], aq[it][1], pp);
        const int row = 32 * a + 16 * it + nid;
        const int cb  = 32 * c + 16 * nt + 4 * qid + row;   // ch=0: l + row
        #pragma unroll
        for (int r = 0; r < 4; ++r)
          ppos[pp_idx(row, (cb + r) % PPC)] = (__bf16)pp[r];
      }
    }
  }
  __syncthreads();

  // ---------------- main loop: 2 barriers per tile, all-single-buffered LDS ----------------
  for (int t = 0; t < NT; ++t) {
    // ======== region A: stage V(t), QK + softmax -> P ========
    // stage V(t) from vr (written region A, read region B)
    #pragma unroll
    for (int e = 0; e < 4; ++e) {
      bf16x4 y = {(__bf16)vr[0][e], (__bf16)vr[1][e], (__bf16)vr[2][e], (__bf16)vr[3][e]};
      *(bf16x4*)&vtb[sw_idx(vh + e, vj)] = y;
    }
    // early issue V(t+1) (HBM latency hidden under the QK/exp compute)
    if (t < 16) {
      const float* vg = &V[((size_t)b * KL_ + m0 + KT * (t + 1) + vj) * H_ + vh];
      #pragma unroll
      for (int e = 0; e < 4; ++e) vr[e] = *(const f32x4*)(vg + e * H_);
    }

    const f32x4 z = {0.f, 0.f, 0.f, 0.f};
    const bool edge = (t == 0) || (t == 16);

    // fused QK^T + softmax per nt (s transient): S^T = mfma(A=K, B=Q)
    #pragma unroll
    for (int nt = 0; nt < 2; ++nt) {
      f32x4 s0 = MFMA32(ak[nt][0], aq[0][0], z);
      s0 = MFMA32(ak[nt][1], aq[0][1], s0);
      f32x4 s1 = MFMA32(ak[nt][0], aq[1][0], z);
      s1 = MFMA32(ak[nt][1], aq[1][1], s1);
      #pragma unroll
      for (int it = 0; it < 2; ++it) {
        const f32x4 sv = it ? s1 : s0;
        const int row = 32 * a + 16 * it + nid;
        const bf16x4 pe4 = *(const bf16x4*)
            &ppos[pp_idx(row, 64 * (t % 3) + 32 * c + 16 * nt + 4 * qid)];
        const int lb = KT * t + 32 * c + 16 * nt + 4 * qid - row;
        bf16x4 pav;
        #pragma unroll
        for (int r = 0; r < 4; ++r) {
          const int l = lb + r;
          float p;
          if (!edge || (unsigned)l < 1024u)
            p = exp2f((sv[r] + (float)pe4[r]) * EXP2_SCALE);
          else
            p = 0.f;
          lpart[it] += p;
          pav[r] = (__bf16)p;
        }
        *(bf16x4*)&Pl[sw_idx(row, 32 * c + 16 * nt + 4 * qid)] = pav;
      }
    }
    __syncthreads();   // barrier1: P(t) + vt(t) visible; ppos slot-t reads done

    // ======== region B: PV from P/vt, QPE(t+1), K(t+1) reload ========
    // K(t+1) A-frags (consumed next iter region A) — issued early for latency
    if (t < 16) {
      const int j1 = m0 + KT * (t + 1);
      #pragma unroll
      for (int nt = 0; nt < 2; ++nt) {
        const float* kg = &K[((size_t)b * KL_ + j1 + 32 * c + 16 * nt + nid) * H_ + 8 * qid];
        const f32x4 k0 = *(const f32x4*)kg;
        const f32x4 k1 = *(const f32x4*)(kg + 4);
        const f32x4 k2 = *(const f32x4*)(kg + 32);
        const f32x4 k3 = *(const f32x4*)(kg + 36);
        #pragma unroll
        for (int j = 0; j < 4; ++j) {
          ak[nt][0][j] = (__bf16)k0[j]; ak[nt][0][4 + j] = (__bf16)k1[j];
          ak[nt][1][j] = (__bf16)k2[j]; ak[nt][1][4 + j] = (__bf16)k3[j];
        }
      }
    }
    // PET loads for chunk t+1
    bf16x8 pf0[2], pf1[2];
    if (t < 15) {
      if constexpr (USE_PET) {
        const __bf16* pb = PET + ((size_t)(t + 1) * 4 + c) * 1024 + (size_t)lane * 16;
        pf0[0] = *(const bf16x8*)pb;          pf1[0] = *(const bf16x8*)(pb + 8);
        pf0[1] = *(const bf16x8*)(pb + 2048); pf1[1] = *(const bf16x8*)(pb + 2048 + 8);
      } else {
        const float* pc = peg + (t + 1) * 64;
        #pragma unroll
        for (int nt = 0; nt < 2; ++nt)
          #pragma unroll
          for (int j = 0; j < 8; ++j) {
            pf0[nt][j] = (__bf16)pc[(size_t)j * L_ + 16 * nt];
            pf1[nt][j] = (__bf16)pc[(size_t)(32 + j) * L_ + 16 * nt];
          }
      }
    }

    // F: PV over ALL 64 kv, h-half owned by d==c.
    //    A-frag: P[32a+16it+nid][16ks+4qid+m]; B-frag: V^T[kv=16ks+4qid+m][h=32c+16ht+nid]
    #pragma unroll
    for (int ks = 0; ks < 4; ++ks) {
      const int kv = 16 * ks + 4 * qid;
      const bf16x4 pa0 = *(const bf16x4*)&Pl[sw_idx(32 * a + nid, kv)];
      const bf16x4 pa1 = *(const bf16x4*)&Pl[sw_idx(32 * a + 16 + nid, kv)];
      const bf16x4 vb0 = *(const bf16x4*)&vtb[sw_idx(32 * c + nid, kv)];
      const bf16x4 vb1 = *(const bf16x4*)&vtb[sw_idx(32 * c + 16 + nid, kv)];
      o[0][0] = mfma_pv(pa0, vb0, o[0][0]);
      o[0][1] = mfma_pv(pa0, vb1, o[0][1]);
      o[1][0] = mfma_pv(pa1, vb0, o[1][0]);
      o[1][1] = mfma_pv(pa1, vb1, o[1][1]);
    }

    // D: QPE chunk t+1 -> ppos slots (t+1)%3,(t+2)%3 (read slot t%3 untouched)
    if (t < 15) {
      const int chb = 64 * (t + 1);
      #pragma unroll
      for (int nt = 0; nt < 2; ++nt) {
        #pragma unroll
        for (int it = 0; it < 2; ++it) {
          f32x4 pp = MFMA32(pf0[nt], aq[it][0], z);
          pp = MFMA32(pf1[nt], aq[it][1], pp);
          const int row = 32 * a + 16 * it + nid;
          const int cb  = chb + 32 * c + 16 * nt + 4 * qid + row;
          #pragma unroll
          for (int r = 0; r < 4; ++r)
            ppos[pp_idx(row, (cb + r) % PPC)] = (__bf16)pp[r];
        }
      }
    }
    __syncthreads();   // barrier2: region-B LDS reads done; next iter may overwrite vt/P
  }

  // ---------------- epilogue: merge c-half row sums, normalize, store ----------------
  float* lsum = (float*)(smem + OFF_LSUM);   // overlay over ppos (all reads done)

  #pragma unroll
  for (int it = 0; it < 2; ++it) {
    float v = lpart[it];
    v += __shfl_xor(v, 16);
    v += __shfl_xor(v, 32);
    lpart[it] = v;
  }
  if (qid == 0) {
    #pragma unroll
    for (int it = 0; it < 2; ++it)
      lsum[c * 64 + 32 * a + 16 * it + nid] = lpart[it];
  }
  __syncthreads();

  float inv[2][4];
  #pragma unroll
  for (int it = 0; it < 2; ++it)
    #pragma unroll
    for (int r = 0; r < 4; ++r) {
      const int row = 32 * a + 16 * it + 4 * qid + r;
      inv[it][r] = 1.f / (lsum[row] + lsum[64 + row]);
    }
  #pragma unroll
  for (int it = 0; it < 2; ++it) {
    #pragma unroll
    for (int ht = 0; ht < 2; ++ht) {
      #pragma unroll
      for (int r = 0; r < 4; ++r) {
        const int row = 32 * a + 16 * it + 4 * qid + r;
        O[((size_t)b * M_ + m0 + row) * H_ + 32 * c + 16 * ht + nid] =
            o[it][ht][r] * inv[it][r];
      }
    }
  }
}

extern "C" void kernel_launch(void* const* d_in, const int* in_sizes, int n_in,
                              void* d_out, int out_size, void* d_ws, size_t ws_size,
                              hipStream_t stream) {
  const float* Q  = (const float*)d_in[0];   // B x M x H
  const float* K  = (const float*)d_in[1];   // B x (M+L) x H
  const float* V  = (const float*)d_in[2];   // B x (M+L) x H
  const float* PE = (const float*)d_in[3];   // 1 x H x L
  float* O = (float*)d_out;                  // B x M x H

  dim3 grid(B_, M_ / BM);                    // 1024 blocks = exactly 4/CU if resident
  if (d_ws != nullptr && ws_size >= PET_BYTES) {
    // init kernel runs in-graph on every launch -> robust to workspace re-poisoning
    __bf16* PET = (__bf16*)d_ws;
    hipLaunchKernelGGL(pe_pack, dim3(256), dim3(256), 0, stream, PE, PET);
    hipLaunchKernelGGL(seqattn_v12<true>, grid, dim3(256), 0, stream, Q, K, V, PE, PET, O);
  } else {
    hipLaunchKernelGGL(seqattn_v12<false>, grid, dim3(256), 0, stream, Q, K, V, PE,
                       (const __bf16*)nullptr, O);
  }
}